// Round 2
// baseline (342.490 us; speedup 1.0000x reference)
//
#include <hip/hip_runtime.h>

// Problem constants (fixed by the reference file).
#define SAMPLES 16
#define NEVENTS (1 << 20)          // 1048576
#define FRAMES  16
#define FSZ     128
#define WIN     (NEVENTS / FRAMES) // 65536 events per frame
#define BINS    (FSZ * FSZ)        // 16384 (y*128 + x)
#define TPB     1024
#define EPT     8                  // events per thread per pipeline step
#define STEPS   (WIN / (EPT * TPB)) // 8 steps, fully unrolled ping-pong

// clang ext-vector types: unlike HIP's float4/int4 wrapper classes these are
// true vector types, accepted by __builtin_nontemporal_{load,store} (R1
// compile fix) and still support .x/.y/.z/.w.
typedef float v4f __attribute__((ext_vector_type(4)));
typedef int   v4i __attribute__((ext_vector_type(4)));

// Structure (carried from prior session, measured best): ONE kernel, one block
// per (frame, sample). Block owns out[f, s, :, :, :] (2*BINS floats = 128 KB
// LDS) exclusively -> pure LDS privatization, no global atomics. Poisoned
// d_out fully overwritten by its owner block.
//
// This revision: the rocprof math (dur 335.7 = 2 poison fills @120.5 + kernel
// ~95us) shows the kernel runs ~3-4x above its pipe-sum model (~25-35us HBM +
// ~10us DS atomics). Theory: load->vmcnt->atomic interleave stalls with only
// 4 waves/SIMD. Fix: explicit ping-pong register pipeline (static reg names,
// 8 ev/thread/step) so next step's 6 loads are in flight across the current
// step's 8 LDS atomics; nt-loads on ev (stream-once) and nt-stores on out
// (write-once) keep L2/L3 for the 16x-reused idx rows.

__device__ __forceinline__ void acc4(float* lds, v4f v, v4i xv, v4i yv) {
    // Branchless plane select from the IEEE sign bit:
    // sign==0 (v>=0) -> pos plane (+BINS), sign==1 -> neg plane (+0).
    // v==+-0 adds 0.0f -> no-op either way.
    const int px = (int)(((__float_as_uint(v.x) >> 31) ^ 1u) << 14);
    const int py = (int)(((__float_as_uint(v.y) >> 31) ^ 1u) << 14);
    const int pz = (int)(((__float_as_uint(v.z) >> 31) ^ 1u) << 14);
    const int pw = (int)(((__float_as_uint(v.w) >> 31) ^ 1u) << 14);
    atomicAdd(&lds[px + yv.x * FSZ + xv.x], fabsf(v.x));
    atomicAdd(&lds[py + yv.y * FSZ + xv.y], fabsf(v.y));
    atomicAdd(&lds[pz + yv.z * FSZ + xv.z], fabsf(v.z));
    atomicAdd(&lds[pw + yv.w * FSZ + xv.w], fabsf(v.w));
}

// Issue one step's loads into a named buffer (a/b halves keep each vector
// load instruction lane-contiguous: 16 B/lane x 1024 threads, coalesced).
#define LOAD(B, step)                                                          \
    v##B##a = __builtin_nontemporal_load(&ev4[(step) * 2 * TPB + tid]);        \
    v##B##b = __builtin_nontemporal_load(&ev4[(step) * 2 * TPB + TPB + tid]);  \
    x##B##a = x4[(step) * 2 * TPB + tid];                                      \
    x##B##b = x4[(step) * 2 * TPB + TPB + tid];                                \
    y##B##a = y4[(step) * 2 * TPB + tid];                                      \
    y##B##b = y4[(step) * 2 * TPB + TPB + tid];

__global__ __launch_bounds__(TPB) void frame_accum_kernel(
    const float* __restrict__ ev,   // [S, N] event_values
    const int*   __restrict__ idx,  // [S, 3, N]; only [0,1,:] (x), [0,2,:] (y) used
    float*       __restrict__ out)  // [F, S, 2, Y, X]
{
    extern __shared__ float lds[];  // [2][BINS]: plane 0 = neg, plane 1 = pos
    const int tid = threadIdx.x;
    const int s = blockIdx.x & (SAMPLES - 1);
    const int f = blockIdx.x >> 4;

    // Zero the private accumulator.
    v4f* lds4 = (v4f*)lds;
    const v4f zero4 = (v4f)(0.f);
#pragma unroll
    for (int i = 0; i < (2 * BINS / 4) / TPB; ++i)   // 8 iters
        lds4[i * TPB + tid] = zero4;
    __syncthreads();

    // This block's event slice: events [f*WIN, (f+1)*WIN), sample s.
    const v4f* ev4 = (const v4f*)(ev  + (size_t)s * NEVENTS + (size_t)f * WIN);
    const v4i* x4  = (const v4i*)(idx + (size_t)NEVENTS      + (size_t)f * WIN); // indices[0,1,:]
    const v4i* y4  = (const v4i*)(idx + (size_t)2 * NEVENTS  + (size_t)f * WIN); // indices[0,2,:]

    v4f vAa, vAb, vBa, vBb;
    v4i xAa, xAb, xBa, xBb, yAa, yAb, yBa, yBb;

    LOAD(A, 0)
#pragma unroll
    for (int st = 0; st < STEPS; st += 2) {
        LOAD(B, st + 1)                      // prefetch next step (B) ...
        acc4(lds, vAa, xAa, yAa);            // ... while A's atomics retire
        acc4(lds, vAb, xAb, yAb);
        if (st + 2 < STEPS) { LOAD(A, st + 2) }
        acc4(lds, vBa, xBa, yBa);
        acc4(lds, vBb, xBb, yBb);
    }
    __syncthreads();

    // Coalesced write of the exclusive slice: out[f, s, p, y, x]; LDS layout
    // (neg plane first) matches the output plane order exactly. Nontemporal:
    // out is write-once, never re-read -> don't displace idx from L2/L3.
    v4f* op4 = (v4f*)(out + ((size_t)(f * SAMPLES + s)) * 2 * BINS);
#pragma unroll
    for (int i = 0; i < (2 * BINS / 4) / TPB; ++i)   // 8 iters
        __builtin_nontemporal_store(lds4[i * TPB + tid], &op4[i * TPB + tid]);
}

extern "C" void kernel_launch(void* const* d_in, const int* in_sizes, int n_in,
                              void* d_out, int out_size, void* d_ws, size_t ws_size,
                              hipStream_t stream) {
    const float* ev  = (const float*)d_in[0];
    const int*   idx = (const int*)d_in[1];
    // d_in[2] = use_soft, fixed 0 (hard path) -> ignored.
    float* out = (float*)d_out;

    // 128 KB dynamic LDS per block; gfx950 GROUP segment is 160 KB/CU.
    (void)hipFuncSetAttribute((const void*)frame_accum_kernel,
                              hipFuncAttributeMaxDynamicSharedMemorySize,
                              2 * BINS * (int)sizeof(float));

    frame_accum_kernel<<<FRAMES * SAMPLES, TPB, 2 * BINS * sizeof(float), stream>>>(
        ev, idx, out);
}